// Round 5
// baseline (752.110 us; speedup 1.0000x reference)
//
#include <hip/hip_runtime.h>
#include <hip/hip_bf16.h>
#include <math.h>

#define HW 512
#define NPIX (HW*HW)

typedef __hip_bfloat16 bf16;
typedef __attribute__((ext_vector_type(8))) unsigned short u16x8;
typedef __attribute__((ext_vector_type(8))) short s16x8;
typedef __attribute__((ext_vector_type(4))) float f32x4;

__device__ __forceinline__ float b2f(bf16 v) { return __bfloat162float(v); }
__device__ __forceinline__ bf16 f2b(float v) { return __float2bfloat16(v); }

union fu { float f; unsigned int u; };
union bu { bf16 b; unsigned short u; };

__device__ __forceinline__ float us2f(unsigned short u) {
    fu c; c.u = ((unsigned int)u) << 16; return c.f;
}

__device__ __forceinline__ void ld_bf8(const bf16* p, float* f) {
    u16x8 u = *(const u16x8*)p;
#pragma unroll
    for (int j = 0; j < 8; j++) { fu c; c.u = ((unsigned int)u[j]) << 16; f[j] = c.f; }
}

__device__ __forceinline__ void st_bf8(bf16* p, const float* f) {
    u16x8 u;
#pragma unroll
    for (int j = 0; j < 8; j++) { bu c; c.b = f2b(f[j]); u[j] = c.u; }
    *(u16x8*)p = u;
}

// ---------------- one-shot prep: pack 3 weight mats to bf16 + zero per-batch S/sumsq ----------------
__global__ __launch_bounds__(256) void k_prep(const float* __restrict__ qkvw,
                                              const float* __restrict__ piw,
                                              const float* __restrict__ fow,
                                              bf16* __restrict__ WQ,
                                              bf16* __restrict__ WP,
                                              bf16* __restrict__ WF,
                                              float* __restrict__ Z0,
                                              float* __restrict__ Z1)
{
    int idx = blockIdx.x*256 + threadIdx.x;
    if (idx < 9216) {
        int oc = idx >> 6, k = idx & 63;
        WQ[idx] = f2b(k < 48 ? qkvw[oc*48 + k] : 0.f);
    } else if (idx < 25600) {
        int j = idx - 9216; int oc = j >> 6, k = j & 63;
        WP[j] = f2b((oc < 254 && k < 48) ? piw[oc*48 + k] : 0.f);
    } else if (idx < 31744) {
        int j = idx - 25600; int oc = j >> 7, k = j & 127;
        WF[j] = f2b(k < 127 ? fow[oc*127 + k] : 0.f);
    } else if (idx < 36544) {
        int j = idx - 31744;
        if (j < 2400) Z0[j] = 0.f; else Z1[j-2400] = 0.f;
    }
}

// ---------------- patch embed: 3x3 conv, 3 -> 48 (wave-per-row, 8px/lane), bf16 out ----------------
__global__ __launch_bounds__(256) void k_pe(const float* __restrict__ x,
                                            const float* __restrict__ w,
                                            bf16* __restrict__ out)
{
    __shared__ float ws[48*27];
    for (int i = threadIdx.x; i < 48*27; i += 256) ws[i] = w[i];
    __syncthreads();
    int lane = threadIdx.x & 63, wv = threadIdx.x >> 6;
    int row = blockIdx.x*4 + wv;
    int col = lane*8;
    float a[3][3][8];
    float lf[3][3], rt[3][3];
#pragma unroll
    for (int c = 0; c < 3; c++)
#pragma unroll
        for (int r = 0; r < 3; r++) {
            int rr = row + r - 1;
            if (rr >= 0 && rr < HW) {
                const float* p = x + (size_t)c*NPIX + rr*HW + col;
                float4 u0 = *(const float4*)p, u1 = *(const float4*)(p+4);
                a[c][r][0]=u0.x; a[c][r][1]=u0.y; a[c][r][2]=u0.z; a[c][r][3]=u0.w;
                a[c][r][4]=u1.x; a[c][r][5]=u1.y; a[c][r][6]=u1.z; a[c][r][7]=u1.w;
            } else {
#pragma unroll
                for (int j = 0; j < 8; j++) a[c][r][j] = 0.f;
            }
            float l = __shfl_up(a[c][r][7], 1);  lf[c][r] = (lane==0)  ? 0.f : l;
            float rv= __shfl_down(a[c][r][0],1); rt[c][r] = (lane==63) ? 0.f : rv;
        }
    for (int oc = 0; oc < 48; oc++) {
        float acc[8];
#pragma unroll
        for (int j = 0; j < 8; j++) acc[j] = 0.f;
#pragma unroll
        for (int c = 0; c < 3; c++)
#pragma unroll
            for (int r = 0; r < 3; r++) {
                float w0 = ws[oc*27 + c*9 + r*3 + 0];
                float w1 = ws[oc*27 + c*9 + r*3 + 1];
                float w2 = ws[oc*27 + c*9 + r*3 + 2];
#pragma unroll
                for (int j = 0; j < 8; j++) {
                    float xm = (j==0) ? lf[c][r] : a[c][r][j-1];
                    float x0 = a[c][r][j];
                    float xp = (j==7) ? rt[c][r] : a[c][r][j+1];
                    acc[j] += w0*xm + w1*x0 + w2*xp;
                }
            }
        st_bf8(out + (size_t)oc*NPIX + row*HW + col, acc);
    }
}

// ---------------- fused LN + 1x1 (48->144) + depthwise 3x3, writing q/k/v directly ----------------
// Block owns an 8x32 output tile. Halo 10x34 = 340 px. A-plane never touches HBM.
#define YPAD 56
#define APAD 360
__global__ __launch_bounds__(256) void k_ln_dw(const bf16* __restrict__ patch,
                                               const float* __restrict__ lnw,
                                               const float* __restrict__ lnb,
                                               const s16x8* __restrict__ wq,   // [144][8 kblocks]
                                               const float* __restrict__ dww,  // [144][9]
                                               bf16* __restrict__ outq)        // 144 planes
{
    __shared__ unsigned short y_lds[352*YPAD];
    __shared__ unsigned short a_lds[48*APAD];
    int t = threadIdx.x;
    int c0 = blockIdx.x*32, r0 = blockIdx.y*8;

    // phase 1: LayerNorm over halo pixels (oob -> 0, matching zero-pad conv)
    for (int hp = t; hp < 352; hp += 256) {
        int hr = hp/34, hc = hp - hr*34;
        int gr = r0 - 1 + hr, gc = c0 - 1 + hc;
        bool ok = (hp < 340) && (gr >= 0) && (gr < HW) && (gc >= 0) && (gc < HW);
        if (ok) {
            int gpx = gr*HW + gc;
            float y[48];
            float mu = 0.f;
#pragma unroll
            for (int i = 0; i < 48; i++) { y[i] = b2f(patch[(size_t)i*NPIX + gpx]); mu += y[i]; }
            mu *= (1.f/48.f);
            float var = 0.f;
#pragma unroll
            for (int i = 0; i < 48; i++) { float d = y[i]-mu; var += d*d; }
            float s = rsqrtf(var*(1.f/48.f) + 1e-5f);
#pragma unroll
            for (int i = 0; i < 48; i++) y[i] = (y[i]-mu)*s*lnw[i] + lnb[i];
#pragma unroll
            for (int kb = 0; kb < 6; kb++) {
                union { u16x8 v; unsigned short us[8]; } pk;
#pragma unroll
                for (int j = 0; j < 8; j++) { bu b; b.b = f2b(y[kb*8+j]); pk.us[j] = b.u; }
                *(u16x8*)&y_lds[hp*YPAD + kb*8] = pk.v;
            }
        } else {
            u16x8 z = {0,0,0,0,0,0,0,0};
#pragma unroll
            for (int kb = 0; kb < 6; kb++) *(u16x8*)&y_lds[hp*YPAD + kb*8] = z;
        }
    }
    __syncthreads();

    int lane = t & 63, wv = t >> 6;
    int q = lane >> 4, n = lane & 15;
    int lr = lane >> 3, lc = lane & 7;

#pragma unroll 1
    for (int cc = 0; cc < 3; cc++) {
        // ---- MFMA chunk: channels [cc*48, cc*48+48) for all 352 halo px ----
        s16x8 a0[3], a1[3];
#pragma unroll
        for (int mi = 0; mi < 3; mi++) {
            int oc = (cc*3 + mi)*16 + n;
            a0[mi] = wq[oc*8 + q];
            a1[mi] = wq[oc*8 + 4 + q];
        }
#pragma unroll 1
        for (int nt = wv; nt < 22; nt += 4) {
            int hp = nt*16 + n;
            s16x8 b0 = *(const s16x8*)&y_lds[hp*YPAD + q*8];
            s16x8 b1 = {0,0,0,0,0,0,0,0};
            if (q < 2) b1 = *(const s16x8*)&y_lds[hp*YPAD + 32 + q*8];
#pragma unroll
            for (int mi = 0; mi < 3; mi++) {
                f32x4 acc = {0.f, 0.f, 0.f, 0.f};
                acc = __builtin_amdgcn_mfma_f32_16x16x32_bf16(a0[mi], b0, acc, 0, 0, 0);
                acc = __builtin_amdgcn_mfma_f32_16x16x32_bf16(a1[mi], b1, acc, 0, 0, 0);
                int mchb = mi*16 + q*4;
#pragma unroll
                for (int r = 0; r < 4; r++) {
                    bu bb; bb.b = f2b(acc[r]);
                    a_lds[(mchb + r)*APAD + hp] = bb.u;
                }
            }
        }
        __syncthreads();

        // ---- depthwise 3x3 from LDS chunk; write q/k/v planes directly ----
#pragma unroll 1
        for (int i = 0; i < 12; i++) {
            int mch = wv + 4*i;
            int ch = cc*48 + mch;
            float wk[9];
#pragma unroll
            for (int k = 0; k < 9; k++) wk[k] = dww[ch*9 + k];
            const unsigned short* ap = &a_lds[mch*APAD];
            float o[4];
#pragma unroll
            for (int j = 0; j < 4; j++) {
                float sm = 0.f;
#pragma unroll
                for (int kr = 0; kr < 3; kr++) {
                    int hb = (lr + kr)*34 + lc*4 + j;
                    float xm = us2f(ap[hb]);
                    float x0 = us2f(ap[hb + 1]);
                    float xp = us2f(ap[hb + 2]);
                    sm += wk[kr*3+0]*xm + wk[kr*3+1]*x0 + wk[kr*3+2]*xp;
                }
                o[j] = sm;
            }
            ushort4 pk;
            { bu b; b.b = f2b(o[0]); pk.x = b.u; }
            { bu b; b.b = f2b(o[1]); pk.y = b.u; }
            { bu b; b.b = f2b(o[2]); pk.z = b.u; }
            { bu b; b.b = f2b(o[3]); pk.w = b.u; }
            *(ushort4*)&outq[(size_t)ch*NPIX + (r0 + lr)*HW + c0 + lc*4] = pk;
        }
        __syncthreads();
    }
}

// ---------------- fused channel-LayerNorm + 1x1 conv via MFMA (48 -> OC), bf16 in/out ----------------
// Epilogue restaged through LDS, 64px per drain: thread t writes plane t's 128B (full L2 line).
template<int OC_PAD, int OC_REAL, int MT_PER_WAVE>
__global__ __launch_bounds__(256) void k_ln_mm_mfma(const bf16* __restrict__ in,
                                                    const float* __restrict__ lnw,
                                                    const float* __restrict__ lnb,
                                                    const s16x8* __restrict__ wpad,  // [OC_PAD][8 blocks]
                                                    bf16* __restrict__ out)
{
    constexpr int NMT = OC_PAD/16;
    __shared__ s16x8 y_lds[256*8];
    __shared__ unsigned short stage[OC_PAD][72];   // 64px rows @144B stride (16B-aligned)
    int t = threadIdx.x;
    int base = blockIdx.x*256;
    int px = base + t;
    float y[48];
    float mu = 0.f;
#pragma unroll
    for (int i = 0; i < 48; i++) { y[i] = b2f(in[(size_t)i*NPIX + px]); mu += y[i]; }
    mu *= (1.f/48.f);
    float var = 0.f;
#pragma unroll
    for (int i = 0; i < 48; i++) { float d = y[i]-mu; var += d*d; }
    float s = rsqrtf(var*(1.f/48.f) + 1e-5f);
#pragma unroll
    for (int i = 0; i < 48; i++) y[i] = (y[i]-mu)*s*lnw[i] + lnb[i];   // lnw/lnb: uniform scalar loads
#pragma unroll
    for (int kb = 0; kb < 8; kb++) {
        union { s16x8 v; unsigned short us[8]; } pk;
#pragma unroll
        for (int j = 0; j < 8; j++) {
            int c = kb*8 + j;
            bu b; b.b = f2b(c < 48 ? y[c] : 0.f);
            pk.us[j] = (c < 48) ? b.u : (unsigned short)0;
        }
        y_lds[t*8 + (kb ^ (t & 7))] = pk.v;
    }
    __syncthreads();

    int lane = t & 63, wv = t >> 6;
    int q = lane >> 4, n = lane & 15;
    s16x8 a[MT_PER_WAVE][2];
#pragma unroll
    for (int mi = 0; mi < MT_PER_WAVE; mi++) {
        int mt = wv + 4*mi;
        if (mt < NMT) {
            int oc = mt*16 + n;
            a[mi][0] = wpad[oc*8 + q];
            a[mi][1] = wpad[oc*8 + 4 + q];
        }
    }
#pragma unroll 1
    for (int g = 0; g < 4; g++) {
#pragma unroll
        for (int sub = 0; sub < 4; sub++) {
            int nt = g*4 + sub;
            int npx = nt*16 + n;
            s16x8 b0 = y_lds[npx*8 + (q ^ (npx & 7))];
            s16x8 b1 = y_lds[npx*8 + ((4 + q) ^ (npx & 7))];
#pragma unroll
            for (int mi = 0; mi < MT_PER_WAVE; mi++) {
                int mt = wv + 4*mi;
                if (mt >= NMT) continue;
                f32x4 acc = {0.f, 0.f, 0.f, 0.f};
                acc = __builtin_amdgcn_mfma_f32_16x16x32_bf16(a[mi][0], b0, acc, 0, 0, 0);
                acc = __builtin_amdgcn_mfma_f32_16x16x32_bf16(a[mi][1], b1, acc, 0, 0, 0);
                int ocb = mt*16 + q*4;
#pragma unroll
                for (int r = 0; r < 4; r++) {
                    bu bb; bb.b = f2b(acc[r]);
                    stage[ocb + r][sub*16 + n] = bb.u;
                }
            }
        }
        __syncthreads();
        if (t < OC_REAL) {
            const u16x8* sp = (const u16x8*)stage[t];
            u16x8 c0 = sp[0], c1 = sp[1], c2 = sp[2], c3 = sp[3];
            u16x8 c4 = sp[4], c5 = sp[5], c6 = sp[6], c7 = sp[7];
            u16x8* op = (u16x8*)(out + (size_t)t*NPIX + base + g*64);
            op[0] = c0; op[1] = c1; op[2] = c2; op[3] = c3;
            op[4] = c4; op[5] = c5; op[6] = c6; op[7] = c7;
        }
        __syncthreads();
    }
}

// ---------------- S = Q K^T (48x48) via MFMA + per-channel sumsq of q,k, fused ----------------
__global__ __launch_bounds__(512) void k_qkt(const bf16* __restrict__ qm,
                                             const bf16* __restrict__ km,
                                             float* __restrict__ S,
                                             float* __restrict__ sumsq)
{
    __shared__ float Sp[8][48][52];
    __shared__ float ssp[8][96];
    int t = threadIdx.x;
    int lane = t & 63, wv = t >> 6;
    int qg = lane >> 4, n = lane & 15;
    size_t px0 = (size_t)(blockIdx.x*8 + wv) * 128 + qg*8;

    f32x4 acc[3][3];
#pragma unroll
    for (int i = 0; i < 3; i++)
#pragma unroll
        for (int j = 0; j < 3; j++) acc[i][j] = (f32x4){0.f, 0.f, 0.f, 0.f};
    float sq[3] = {0.f, 0.f, 0.f}, sk[3] = {0.f, 0.f, 0.f};

#pragma unroll 2
    for (int s = 0; s < 4; s++) {
        size_t p = px0 + s*32;
        s16x8 qa[3], ka[3];
#pragma unroll
        for (int i = 0; i < 3; i++) {
            qa[i] = *(const s16x8*)&qm[(size_t)(16*i + n)*NPIX + p];
            ka[i] = *(const s16x8*)&km[(size_t)(16*i + n)*NPIX + p];
        }
#pragma unroll
        for (int i = 0; i < 3; i++)
#pragma unroll
            for (int j = 0; j < 3; j++)
                acc[i][j] = __builtin_amdgcn_mfma_f32_16x16x32_bf16(qa[i], ka[j], acc[i][j], 0, 0, 0);
#pragma unroll
        for (int i = 0; i < 3; i++) {
            union { s16x8 v; unsigned short us[8]; } uq, uk;
            uq.v = qa[i]; uk.v = ka[i];
#pragma unroll
            for (int j = 0; j < 8; j++) {
                fu cq; cq.u = ((unsigned int)uq.us[j]) << 16; sq[i] += cq.f*cq.f;
                fu ck; ck.u = ((unsigned int)uk.us[j]) << 16; sk[i] += ck.f*ck.f;
            }
        }
    }

#pragma unroll
    for (int i = 0; i < 3; i++)
#pragma unroll
        for (int j = 0; j < 3; j++)
#pragma unroll
            for (int r = 0; r < 4; r++)
                Sp[wv][16*i + qg*4 + r][16*j + n] = acc[i][j][r];
#pragma unroll
    for (int i = 0; i < 3; i++) {
        float a = sq[i], b = sk[i];
        a += __shfl_down(a, 32); a += __shfl_down(a, 16);
        b += __shfl_down(b, 32); b += __shfl_down(b, 16);
        if (lane < 16) { ssp[wv][16*i + lane] = a; ssp[wv][48 + 16*i + lane] = b; }
    }
    __syncthreads();

    for (int idx = t; idx < 2304; idx += 512) {
        int r = idx / 48, c = idx - r*48;
        float v = 0.f;
#pragma unroll
        for (int w = 0; w < 8; w++) v += Sp[w][r][c];
        atomicAdd(&S[idx], v);
    }
    if (t < 96) {
        float v = 0.f;
#pragma unroll
        for (int w = 0; w < 8; w++) v += ssp[w][t];
        atomicAdd(&sumsq[t], v);
    }
}

// ---------------- finalize: normalize, softmax, M = po_w @ attn ----------------
__global__ __launch_bounds__(256) void k_attn_final(const float* __restrict__ S,
                                                    const float* __restrict__ sumsq,
                                                    const float* __restrict__ po_w,
                                                    const float* __restrict__ temp,
                                                    float* __restrict__ M)
{
    __shared__ float attn[48][48];
    __shared__ float nrm[96];
    int t = threadIdx.x;
    if (t < 96) nrm[t] = fmaxf(sqrtf(sumsq[t]), 1e-12f);
    __syncthreads();
    float tmp = temp[0];
    if (t < 48) {
        float row[48];
        float mx = -1e30f;
#pragma unroll
        for (int d = 0; d < 48; d++) {
            float l = S[t*48+d] / (nrm[t]*nrm[48+d]) * tmp;
            row[d] = l; mx = fmaxf(mx, l);
        }
        float sum = 0.f;
#pragma unroll
        for (int d = 0; d < 48; d++) { float e = expf(row[d]-mx); sum += e; row[d] = e; }
        float inv = 1.f/sum;
#pragma unroll
        for (int d = 0; d < 48; d++) attn[t][d] = row[d]*inv;
    }
    __syncthreads();
    for (int idx = t; idx < 2304; idx += 256) {
        int cp = idx/48, d = idx%48;
        float acc = 0.f;
#pragma unroll
        for (int c = 0; c < 48; c++) acc += po_w[cp*48+c] * attn[c][d];
        M[idx] = acc;
    }
}

// ---------------- first = patch + M @ v (in place over bf16 patch, 2px/thread) ----------------
__global__ __launch_bounds__(256) void k_attnv(const bf16* __restrict__ v,
                                               const float* __restrict__ M,
                                               bf16* __restrict__ patch)
{
    __shared__ float Ms[48*48];
    for (int i = threadIdx.x; i < 2304; i += 256) Ms[i] = M[i];
    __syncthreads();
    int p = (blockIdx.x*256 + threadIdx.x)*2;
    float v0[48], v1[48];
#pragma unroll
    for (int i = 0; i < 48; i++) {
        unsigned int word = *(const unsigned int*)&v[(size_t)i*NPIX + p];
        fu c0, c1; c0.u = word << 16; c1.u = word & 0xffff0000u;
        v0[i] = c0.f; v1[i] = c1.f;
    }
    for (int oc = 0; oc < 48; oc++) {
        const float4* wr = (const float4*)&Ms[oc*48];
        float a0 = 0.f, a1 = 0.f;
#pragma unroll
        for (int i = 0; i < 12; i++) {
            float4 w4 = wr[i];
            a0 += w4.x*v0[4*i] + w4.y*v0[4*i+1] + w4.z*v0[4*i+2] + w4.w*v0[4*i+3];
            a1 += w4.x*v1[4*i] + w4.y*v1[4*i+1] + w4.z*v1[4*i+2] + w4.w*v1[4*i+3];
        }
        unsigned int* pp = (unsigned int*)&patch[(size_t)oc*NPIX + p];
        unsigned int old = *pp;
        fu f0, f1; f0.u = old << 16; f1.u = old & 0xffff0000u;
        bu b0, b1; b0.b = f2b(f0.f + a0); b1.b = f2b(f1.f + a1);
        *pp = (unsigned int)b0.u | ((unsigned int)b1.u << 16);
    }
}

// ---------------- depthwise 3x3 both halves + gelu(x1)*x2, rolling window: 8 rows/wave ----------------
__global__ __launch_bounds__(256) void k_dw_glu(const bf16* __restrict__ h1,
                                                const float* __restrict__ w,
                                                bf16* __restrict__ g)
{
    int ch = blockIdx.y;   // 0..126
    int lane = threadIdx.x & 63, wv = threadIdx.x >> 6;
    int row0 = blockIdx.x*32 + wv*8;
    int col = lane*8;
    float w1[9], w2[9];
#pragma unroll
    for (int i = 0; i < 9; i++) { w1[i] = w[ch*9+i]; w2[i] = w[(ch+127)*9+i]; }
    const bf16* i1 = h1 + (size_t)ch*NPIX;
    const bf16* i2 = h1 + (size_t)(ch+127)*NPIX;
    bf16* op = g + (size_t)ch*NPIX;
    float aa[3][8], bb[3][8];
    float lfa[3], rta[3], lfb[3], rtb[3];

    auto loadrow = [&](int s, int rr) {
        if (rr >= 0 && rr < HW) {
            ld_bf8(i1 + rr*HW + col, aa[s]);
            ld_bf8(i2 + rr*HW + col, bb[s]);
        } else {
#pragma unroll
            for (int j = 0; j < 8; j++) { aa[s][j] = 0.f; bb[s][j] = 0.f; }
        }
        float l1 = __shfl_up(aa[s][7],1);   lfa[s] = (lane==0)  ? 0.f : l1;
        float r1 = __shfl_down(aa[s][0],1); rta[s] = (lane==63) ? 0.f : r1;
        float l2 = __shfl_up(bb[s][7],1);   lfb[s] = (lane==0)  ? 0.f : l2;
        float r2 = __shfl_down(bb[s][0],1); rtb[s] = (lane==63) ? 0.f : r2;
    };
    loadrow(0, row0-1);
    loadrow(1, row0);
#pragma unroll
    for (int r = 0; r < 8; r++) {
        loadrow((r+2)%3, row0 + r + 1);
        const int s0 = r%3, s1 = (r+1)%3, s2 = (r+2)%3;
        float o[8];
#pragma unroll
        for (int j = 0; j < 8; j++) {
            float sum1 = 0.f, sum2 = 0.f;
#pragma unroll
            for (int kr = 0; kr < 3; kr++) {
                const int ss = (kr==0) ? s0 : (kr==1) ? s1 : s2;
                float xm = (j==0) ? lfa[ss] : aa[ss][j-1];
                float x0 = aa[ss][j];
                float xp = (j==7) ? rta[ss] : aa[ss][j+1];
                sum1 += w1[kr*3+0]*xm + w1[kr*3+1]*x0 + w1[kr*3+2]*xp;
                float ym = (j==0) ? lfb[ss] : bb[ss][j-1];
                float y0 = bb[ss][j];
                float yp = (j==7) ? rtb[ss] : bb[ss][j+1];
                sum2 += w2[kr*3+0]*ym + w2[kr*3+1]*y0 + w2[kr*3+2]*yp;
            }
            float ge = 0.5f*sum1*(1.f + erff(sum1*0.70710678118654752f));
            o[j] = ge*sum2;
        }
        st_bf8(op + (row0 + r)*HW + col, o);
    }
}

// ---------------- fo 1x1 conv (127 -> 48) via MFMA + residual, fp32 out ----------------
__global__ __launch_bounds__(256) void k_fo_mfma(const bf16* __restrict__ g,
                                                 const s16x8* __restrict__ wfo,   // [48][16 blocks]
                                                 const bf16* __restrict__ first,
                                                 float* __restrict__ out)
{
    __shared__ s16x8 glds[256*16];   // 64 KB, swizzled
    int t = threadIdx.x;
    int base = blockIdx.x*256;
    int px = base + t;
#pragma unroll
    for (int kb = 0; kb < 16; kb++) {
        union { s16x8 v; unsigned short us[8]; } pk;
#pragma unroll
        for (int j = 0; j < 8; j++) {
            int c = kb*8 + j;
            if (c < 127) { bu b; b.b = g[(size_t)c*NPIX + px]; pk.us[j] = b.u; }
            else pk.us[j] = 0;
        }
        glds[t*16 + (kb ^ (t & 15))] = pk.v;
    }
    __syncthreads();
    int lane = t & 63, wv = t >> 6;
    int q = lane >> 4, n = lane & 15;
    s16x8 a[3][4];
#pragma unroll
    for (int mt = 0; mt < 3; mt++) {
        int oc = mt*16 + n;
#pragma unroll
        for (int kc = 0; kc < 4; kc++)
            a[mt][kc] = wfo[oc*16 + kc*4 + q];
    }
#pragma unroll 1
    for (int ni = 0; ni < 4; ni++) {
        int nt = wv*4 + ni;
        int npx = nt*16 + n;
        s16x8 b[4];
#pragma unroll
        for (int kc = 0; kc < 4; kc++)
            b[kc] = glds[npx*16 + ((kc*4 + q) ^ (npx & 15))];
        size_t pxg = base + npx;
#pragma unroll
        for (int mt = 0; mt < 3; mt++) {
            f32x4 acc = {0.f, 0.f, 0.f, 0.f};
#pragma unroll
            for (int kc = 0; kc < 4; kc++)
                acc = __builtin_amdgcn_mfma_f32_16x16x32_bf16(a[mt][kc], b[kc], acc, 0, 0, 0);
            int ocb = mt*16 + q*4;
#pragma unroll
            for (int r = 0; r < 4; r++) {
                int oc = ocb + r;
                out[(size_t)oc*NPIX + pxg] = b2f(first[(size_t)oc*NPIX + pxg]) + acc[r];
            }
        }
    }
}

extern "C" void kernel_launch(void* const* d_in, const int* in_sizes, int n_in,
                              void* d_out, int out_size, void* d_ws, size_t ws_size,
                              hipStream_t stream)
{
    const float* x     = (const float*)d_in[0];
    const float* pe_w  = (const float*)d_in[1];
    const float* n1w   = (const float*)d_in[2];
    const float* n1b   = (const float*)d_in[3];
    const float* temp  = (const float*)d_in[4];
    const float* qkvw  = (const float*)d_in[5];
    const float* qkvdw = (const float*)d_in[6];
    const float* pow_  = (const float*)d_in[7];
    const float* n2w   = (const float*)d_in[8];
    const float* n2b   = (const float*)d_in[9];
    const float* piw   = (const float*)d_in[10];
    const float* ffndw = (const float*)d_in[11];
    const float* fow   = (const float*)d_in[12];
    float* out = (float*)d_out;

    bf16*  Pb = (bf16*)d_ws;
    bf16*  A  = Pb + (size_t)48*NPIX;          // region reused: H1 (254 planes)
    bf16*  Bq = A + (size_t)144*NPIX;          // qkv post-dw (q,k,v)
    bf16*  H1 = A;
    bf16*  G  = A + (size_t)254*NPIX;
    bf16*  WQ = A + (size_t)381*NPIX;          // 144*64
    bf16*  WP = WQ + 144*64;                   // 256*64
    bf16*  WF = WP + 256*64;                   // 48*128
    float* SM0 = (float*)(A + (size_t)384*NPIX);   // per-batch: sumsq[96], S[2304], M[2304]
    float* SM1 = SM0 + 4704;

    dim3 blk(256);
    int nb1 = NPIX/256;   // 1px/thread MFMA kernels
    int nb2 = NPIX/512;   // 2px/thread (attnv)
    int nr  = HW/4;       // k_pe: 4 rows/block
    int nrw = HW/32;      // rolling dw kernels: 32 rows/block

    k_prep<<<dim3(143), blk, 0, stream>>>(qkvw, piw, fow, WQ, WP, WF, SM0, SM1);

    for (int b = 0; b < 2; b++) {
        const float* xb   = x   + (size_t)b*3*NPIX;
        float*       outb = out + (size_t)b*48*NPIX;
        float* SMb   = b ? SM1 : SM0;
        float* sumsq = SMb;
        float* S     = SMb + 96;
        float* M     = SMb + 2400;

        k_pe<<<dim3(nr), blk, 0, stream>>>(xb, pe_w, Pb);
        k_ln_dw<<<dim3(HW/32, HW/8), blk, 0, stream>>>(Pb, n1w, n1b, (const s16x8*)WQ, qkvdw, Bq);
        k_qkt<<<dim3(NPIX/1024), dim3(512), 0, stream>>>(Bq, Bq + (size_t)48*NPIX, S, sumsq);
        k_attn_final<<<dim3(1), blk, 0, stream>>>(S, sumsq, pow_, temp, M);
        k_attnv<<<dim3(nb2), blk, 0, stream>>>(Bq + (size_t)96*NPIX, M, Pb);
        k_ln_mm_mfma<256,254,4><<<dim3(nb1), blk, 0, stream>>>(Pb, n2w, n2b, (const s16x8*)WP, H1);
        k_dw_glu<<<dim3(nrw, 127), blk, 0, stream>>>(H1, ffndw, G);
        k_fo_mfma<<<dim3(nb1), blk, 0, stream>>>(G, (const s16x8*)WF, Pb, outb);
    }
}

// Round 6
// 711.731 us; speedup vs baseline: 1.0567x; 1.0567x over previous
//
#include <hip/hip_runtime.h>
#include <hip/hip_bf16.h>
#include <math.h>

#define HW 512
#define NPIX (HW*HW)

typedef __hip_bfloat16 bf16;
typedef __attribute__((ext_vector_type(8))) unsigned short u16x8;
typedef __attribute__((ext_vector_type(8))) short s16x8;
typedef __attribute__((ext_vector_type(4))) float f32x4;

__device__ __forceinline__ float b2f(bf16 v) { return __bfloat162float(v); }
__device__ __forceinline__ bf16 f2b(float v) { return __float2bfloat16(v); }

union fu { float f; unsigned int u; };
union bu { bf16 b; unsigned short u; };

__device__ __forceinline__ float us2f(unsigned short u) {
    fu c; c.u = ((unsigned int)u) << 16; return c.f;
}

__device__ __forceinline__ void ld_bf8(const bf16* p, float* f) {
    u16x8 u = *(const u16x8*)p;
#pragma unroll
    for (int j = 0; j < 8; j++) { fu c; c.u = ((unsigned int)u[j]) << 16; f[j] = c.f; }
}

__device__ __forceinline__ void st_bf8(bf16* p, const float* f) {
    u16x8 u;
#pragma unroll
    for (int j = 0; j < 8; j++) { bu c; c.b = f2b(f[j]); u[j] = c.u; }
    *(u16x8*)p = u;
}

// ---------------- one-shot prep: pack 3 weight mats to bf16 + zero per-batch S/sumsq ----------------
__global__ __launch_bounds__(256) void k_prep(const float* __restrict__ qkvw,
                                              const float* __restrict__ piw,
                                              const float* __restrict__ fow,
                                              bf16* __restrict__ WQ,
                                              bf16* __restrict__ WP,
                                              bf16* __restrict__ WF,
                                              float* __restrict__ Z0,
                                              float* __restrict__ Z1)
{
    int idx = blockIdx.x*256 + threadIdx.x;
    if (idx < 9216) {
        int oc = idx >> 6, k = idx & 63;
        WQ[idx] = f2b(k < 48 ? qkvw[oc*48 + k] : 0.f);
    } else if (idx < 25600) {
        int j = idx - 9216; int oc = j >> 6, k = j & 63;
        WP[j] = f2b((oc < 254 && k < 48) ? piw[oc*48 + k] : 0.f);
    } else if (idx < 31744) {
        int j = idx - 25600; int oc = j >> 7, k = j & 127;
        WF[j] = f2b(k < 127 ? fow[oc*127 + k] : 0.f);
    } else if (idx < 36544) {
        int j = idx - 31744;
        if (j < 2400) Z0[j] = 0.f; else Z1[j-2400] = 0.f;
    }
}

// ---------------- patch embed: 3x3 conv, 3 -> 48 (wave-per-row, 8px/lane), bf16 out ----------------
__global__ __launch_bounds__(256) void k_pe(const float* __restrict__ x,
                                            const float* __restrict__ w,
                                            bf16* __restrict__ out)
{
    __shared__ float ws[48*27];
    for (int i = threadIdx.x; i < 48*27; i += 256) ws[i] = w[i];
    __syncthreads();
    int lane = threadIdx.x & 63, wv = threadIdx.x >> 6;
    int row = blockIdx.x*4 + wv;
    int col = lane*8;
    float a[3][3][8];
    float lf[3][3], rt[3][3];
#pragma unroll
    for (int c = 0; c < 3; c++)
#pragma unroll
        for (int r = 0; r < 3; r++) {
            int rr = row + r - 1;
            if (rr >= 0 && rr < HW) {
                const float* p = x + (size_t)c*NPIX + rr*HW + col;
                float4 u0 = *(const float4*)p, u1 = *(const float4*)(p+4);
                a[c][r][0]=u0.x; a[c][r][1]=u0.y; a[c][r][2]=u0.z; a[c][r][3]=u0.w;
                a[c][r][4]=u1.x; a[c][r][5]=u1.y; a[c][r][6]=u1.z; a[c][r][7]=u1.w;
            } else {
#pragma unroll
                for (int j = 0; j < 8; j++) a[c][r][j] = 0.f;
            }
            float l = __shfl_up(a[c][r][7], 1);  lf[c][r] = (lane==0)  ? 0.f : l;
            float rv= __shfl_down(a[c][r][0],1); rt[c][r] = (lane==63) ? 0.f : rv;
        }
    for (int oc = 0; oc < 48; oc++) {
        float acc[8];
#pragma unroll
        for (int j = 0; j < 8; j++) acc[j] = 0.f;
#pragma unroll
        for (int c = 0; c < 3; c++)
#pragma unroll
            for (int r = 0; r < 3; r++) {
                float w0 = ws[oc*27 + c*9 + r*3 + 0];
                float w1 = ws[oc*27 + c*9 + r*3 + 1];
                float w2 = ws[oc*27 + c*9 + r*3 + 2];
#pragma unroll
                for (int j = 0; j < 8; j++) {
                    float xm = (j==0) ? lf[c][r] : a[c][r][j-1];
                    float x0 = a[c][r][j];
                    float xp = (j==7) ? rt[c][r] : a[c][r][j+1];
                    acc[j] += w0*xm + w1*x0 + w2*xp;
                }
            }
        st_bf8(out + (size_t)oc*NPIX + row*HW + col, acc);
    }
}

// ---------------- fused LN + 1x1 (48->144) + depthwise 3x3, writing q/k/v directly ----------------
// Block owns an 8x32 output tile. Halo 10x34 = 340 px.
// a_lds: row-padded [48ch][11 rows][40] (stride 440 u16): dw phase uses aligned vector reads.
#define YPAD 56
#define CHS 440
__global__ __launch_bounds__(256) void k_ln_dw(const bf16* __restrict__ patch,
                                               const float* __restrict__ lnw,
                                               const float* __restrict__ lnb,
                                               const s16x8* __restrict__ wq,   // [144][8 kblocks]
                                               const float* __restrict__ dww,  // [144][9]
                                               bf16* __restrict__ outq)        // 144 planes
{
    __shared__ unsigned short y_lds[352*YPAD];
    __shared__ unsigned short a_lds[48*CHS];
    int t = threadIdx.x;
    int c0 = blockIdx.x*32, r0 = blockIdx.y*8;

    // phase 1: LayerNorm over halo pixels (oob -> 0, matching zero-pad conv)
    for (int hp = t; hp < 352; hp += 256) {
        int hr = hp/34, hc = hp - hr*34;
        int gr = r0 - 1 + hr, gc = c0 - 1 + hc;
        bool ok = (hp < 340) && (gr >= 0) && (gr < HW) && (gc >= 0) && (gc < HW);
        if (ok) {
            int gpx = gr*HW + gc;
            float y[48];
            float mu = 0.f;
#pragma unroll
            for (int i = 0; i < 48; i++) { y[i] = b2f(patch[(size_t)i*NPIX + gpx]); mu += y[i]; }
            mu *= (1.f/48.f);
            float var = 0.f;
#pragma unroll
            for (int i = 0; i < 48; i++) { float d = y[i]-mu; var += d*d; }
            float s = rsqrtf(var*(1.f/48.f) + 1e-5f);
#pragma unroll
            for (int i = 0; i < 48; i++) y[i] = (y[i]-mu)*s*lnw[i] + lnb[i];
#pragma unroll
            for (int kb = 0; kb < 6; kb++) {
                union { u16x8 v; unsigned short us[8]; } pk;
#pragma unroll
                for (int j = 0; j < 8; j++) { bu b; b.b = f2b(y[kb*8+j]); pk.us[j] = b.u; }
                *(u16x8*)&y_lds[hp*YPAD + kb*8] = pk.v;
            }
        } else {
            u16x8 z = {0,0,0,0,0,0,0,0};
#pragma unroll
            for (int kb = 0; kb < 6; kb++) *(u16x8*)&y_lds[hp*YPAD + kb*8] = z;
        }
    }
    __syncthreads();

    int lane = t & 63, wv = t >> 6;
    int q = lane >> 4, n = lane & 15;
    int ch2 = lane >> 5;          // 0..1 : channel half within wave
    int idx5 = lane & 31;
    int orow = idx5 >> 2;         // 0..7 : output row in tile
    int cg   = idx5 & 3;          // 0..3 : 8-px column group

#pragma unroll 1
    for (int cc = 0; cc < 3; cc++) {
        // ---- MFMA chunk: channels [cc*48, cc*48+48) for all 352 halo px ----
        s16x8 a0[3], a1[3];
#pragma unroll
        for (int mi = 0; mi < 3; mi++) {
            int oc = (cc*3 + mi)*16 + n;
            a0[mi] = wq[oc*8 + q];
            a1[mi] = wq[oc*8 + 4 + q];
        }
#pragma unroll 1
        for (int nt = wv; nt < 22; nt += 4) {
            int hp = nt*16 + n;
            int hr = hp/34, hc = hp - hr*34;     // padded-layout coords (junk hp>=340 -> row 10)
            int abase = hr*40 + hc;
            s16x8 b0 = *(const s16x8*)&y_lds[hp*YPAD + q*8];
            s16x8 b1 = {0,0,0,0,0,0,0,0};
            if (q < 2) b1 = *(const s16x8*)&y_lds[hp*YPAD + 32 + q*8];
#pragma unroll
            for (int mi = 0; mi < 3; mi++) {
                f32x4 acc = {0.f, 0.f, 0.f, 0.f};
                acc = __builtin_amdgcn_mfma_f32_16x16x32_bf16(a0[mi], b0, acc, 0, 0, 0);
                acc = __builtin_amdgcn_mfma_f32_16x16x32_bf16(a1[mi], b1, acc, 0, 0, 0);
                int mchb = mi*16 + q*4;
#pragma unroll
                for (int r = 0; r < 4; r++) {
                    bu bb; bb.b = f2b(acc[r]);
                    a_lds[(mchb + r)*CHS + abase] = bb.u;
                }
            }
        }
        __syncthreads();

        // ---- depthwise 3x3: vector reads from padded LDS; 8 px/lane, 2 ch/wave ----
#pragma unroll 1
        for (int i = 0; i < 6; i++) {
            int chl = i*8 + wv*2 + ch2;       // 0..47
            int ch  = cc*48 + chl;
            float wk[9];
#pragma unroll
            for (int k = 0; k < 9; k++) wk[k] = dww[ch*9 + k];
            const unsigned short* ap = &a_lds[chl*CHS];
            float win[3][10];
#pragma unroll
            for (int kr = 0; kr < 3; kr++) {
                u16x8 A = *(const u16x8*)&ap[(orow + kr)*40 + cg*8];
                unsigned int B = *(const unsigned int*)&ap[(orow + kr)*40 + cg*8 + 8];
#pragma unroll
                for (int j = 0; j < 8; j++) win[kr][j] = us2f(A[j]);
                win[kr][8] = us2f((unsigned short)(B & 0xffffu));
                win[kr][9] = us2f((unsigned short)(B >> 16));
            }
            u16x8 pk;
#pragma unroll
            for (int j = 0; j < 8; j++) {
                float sm = 0.f;
#pragma unroll
                for (int kr = 0; kr < 3; kr++)
                    sm += wk[kr*3+0]*win[kr][j] + wk[kr*3+1]*win[kr][j+1] + wk[kr*3+2]*win[kr][j+2];
                bu b; b.b = f2b(sm); pk[j] = b.u;
            }
            *(u16x8*)&outq[(size_t)ch*NPIX + (r0 + orow)*HW + c0 + cg*8] = pk;
        }
        __syncthreads();
    }
}

// ---------------- fused channel-LayerNorm + 1x1 conv via MFMA (48 -> OC), bf16 in/out ----------------
// Epilogue restaged through LDS, 64px per drain: thread t writes plane t's 128B (full L2 line).
template<int OC_PAD, int OC_REAL, int MT_PER_WAVE>
__global__ __launch_bounds__(256) void k_ln_mm_mfma(const bf16* __restrict__ in,
                                                    const float* __restrict__ lnw,
                                                    const float* __restrict__ lnb,
                                                    const s16x8* __restrict__ wpad,  // [OC_PAD][8 blocks]
                                                    bf16* __restrict__ out)
{
    constexpr int NMT = OC_PAD/16;
    __shared__ s16x8 y_lds[256*8];
    __shared__ unsigned short stage[OC_PAD][72];   // 64px rows @144B stride (16B-aligned)
    int t = threadIdx.x;
    int base = blockIdx.x*256;
    int px = base + t;
    float y[48];
    float mu = 0.f;
#pragma unroll
    for (int i = 0; i < 48; i++) { y[i] = b2f(in[(size_t)i*NPIX + px]); mu += y[i]; }
    mu *= (1.f/48.f);
    float var = 0.f;
#pragma unroll
    for (int i = 0; i < 48; i++) { float d = y[i]-mu; var += d*d; }
    float s = rsqrtf(var*(1.f/48.f) + 1e-5f);
#pragma unroll
    for (int i = 0; i < 48; i++) y[i] = (y[i]-mu)*s*lnw[i] + lnb[i];   // lnw/lnb: uniform scalar loads
#pragma unroll
    for (int kb = 0; kb < 8; kb++) {
        union { s16x8 v; unsigned short us[8]; } pk;
#pragma unroll
        for (int j = 0; j < 8; j++) {
            int c = kb*8 + j;
            bu b; b.b = f2b(c < 48 ? y[c] : 0.f);
            pk.us[j] = (c < 48) ? b.u : (unsigned short)0;
        }
        y_lds[t*8 + (kb ^ (t & 7))] = pk.v;
    }
    __syncthreads();

    int lane = t & 63, wv = t >> 6;
    int q = lane >> 4, n = lane & 15;
    s16x8 a[MT_PER_WAVE][2];
#pragma unroll
    for (int mi = 0; mi < MT_PER_WAVE; mi++) {
        int mt = wv + 4*mi;
        if (mt < NMT) {
            int oc = mt*16 + n;
            a[mi][0] = wpad[oc*8 + q];
            a[mi][1] = wpad[oc*8 + 4 + q];
        }
    }
#pragma unroll 1
    for (int g = 0; g < 4; g++) {
#pragma unroll
        for (int sub = 0; sub < 4; sub++) {
            int nt = g*4 + sub;
            int npx = nt*16 + n;
            s16x8 b0 = y_lds[npx*8 + (q ^ (npx & 7))];
            s16x8 b1 = y_lds[npx*8 + ((4 + q) ^ (npx & 7))];
#pragma unroll
            for (int mi = 0; mi < MT_PER_WAVE; mi++) {
                int mt = wv + 4*mi;
                if (mt >= NMT) continue;
                f32x4 acc = {0.f, 0.f, 0.f, 0.f};
                acc = __builtin_amdgcn_mfma_f32_16x16x32_bf16(a[mi][0], b0, acc, 0, 0, 0);
                acc = __builtin_amdgcn_mfma_f32_16x16x32_bf16(a[mi][1], b1, acc, 0, 0, 0);
                int ocb = mt*16 + q*4;
#pragma unroll
                for (int r = 0; r < 4; r++) {
                    bu bb; bb.b = f2b(acc[r]);
                    stage[ocb + r][sub*16 + n] = bb.u;
                }
            }
        }
        __syncthreads();
        if (t < OC_REAL) {
            const u16x8* sp = (const u16x8*)stage[t];
            u16x8 c0 = sp[0], c1 = sp[1], c2 = sp[2], c3 = sp[3];
            u16x8 c4 = sp[4], c5 = sp[5], c6 = sp[6], c7 = sp[7];
            u16x8* op = (u16x8*)(out + (size_t)t*NPIX + base + g*64);
            op[0] = c0; op[1] = c1; op[2] = c2; op[3] = c3;
            op[4] = c4; op[5] = c5; op[6] = c6; op[7] = c7;
        }
        __syncthreads();
    }
}

// ---------------- S = Q K^T (48x48) via MFMA + per-channel sumsq of q,k, fused ----------------
__global__ __launch_bounds__(512) void k_qkt(const bf16* __restrict__ qm,
                                             const bf16* __restrict__ km,
                                             float* __restrict__ S,
                                             float* __restrict__ sumsq)
{
    __shared__ float Sp[8][48][52];
    __shared__ float ssp[8][96];
    int t = threadIdx.x;
    int lane = t & 63, wv = t >> 6;
    int qg = lane >> 4, n = lane & 15;
    size_t px0 = (size_t)(blockIdx.x*8 + wv) * 128 + qg*8;

    f32x4 acc[3][3];
#pragma unroll
    for (int i = 0; i < 3; i++)
#pragma unroll
        for (int j = 0; j < 3; j++) acc[i][j] = (f32x4){0.f, 0.f, 0.f, 0.f};
    float sq[3] = {0.f, 0.f, 0.f}, sk[3] = {0.f, 0.f, 0.f};

#pragma unroll 2
    for (int s = 0; s < 4; s++) {
        size_t p = px0 + s*32;
        s16x8 qa[3], ka[3];
#pragma unroll
        for (int i = 0; i < 3; i++) {
            qa[i] = *(const s16x8*)&qm[(size_t)(16*i + n)*NPIX + p];
            ka[i] = *(const s16x8*)&km[(size_t)(16*i + n)*NPIX + p];
        }
#pragma unroll
        for (int i = 0; i < 3; i++)
#pragma unroll
            for (int j = 0; j < 3; j++)
                acc[i][j] = __builtin_amdgcn_mfma_f32_16x16x32_bf16(qa[i], ka[j], acc[i][j], 0, 0, 0);
#pragma unroll
        for (int i = 0; i < 3; i++) {
            union { s16x8 v; unsigned short us[8]; } uq, uk;
            uq.v = qa[i]; uk.v = ka[i];
#pragma unroll
            for (int j = 0; j < 8; j++) {
                fu cq; cq.u = ((unsigned int)uq.us[j]) << 16; sq[i] += cq.f*cq.f;
                fu ck; ck.u = ((unsigned int)uk.us[j]) << 16; sk[i] += ck.f*ck.f;
            }
        }
    }

#pragma unroll
    for (int i = 0; i < 3; i++)
#pragma unroll
        for (int j = 0; j < 3; j++)
#pragma unroll
            for (int r = 0; r < 4; r++)
                Sp[wv][16*i + qg*4 + r][16*j + n] = acc[i][j][r];
#pragma unroll
    for (int i = 0; i < 3; i++) {
        float a = sq[i], b = sk[i];
        a += __shfl_down(a, 32); a += __shfl_down(a, 16);
        b += __shfl_down(b, 32); b += __shfl_down(b, 16);
        if (lane < 16) { ssp[wv][16*i + lane] = a; ssp[wv][48 + 16*i + lane] = b; }
    }
    __syncthreads();

    for (int idx = t; idx < 2304; idx += 512) {
        int r = idx / 48, c = idx - r*48;
        float v = 0.f;
#pragma unroll
        for (int w = 0; w < 8; w++) v += Sp[w][r][c];
        atomicAdd(&S[idx], v);
    }
    if (t < 96) {
        float v = 0.f;
#pragma unroll
        for (int w = 0; w < 8; w++) v += ssp[w][t];
        atomicAdd(&sumsq[t], v);
    }
}

// ---------------- finalize: normalize, softmax, M = po_w @ attn ----------------
__global__ __launch_bounds__(256) void k_attn_final(const float* __restrict__ S,
                                                    const float* __restrict__ sumsq,
                                                    const float* __restrict__ po_w,
                                                    const float* __restrict__ temp,
                                                    float* __restrict__ M)
{
    __shared__ float attn[48][48];
    __shared__ float nrm[96];
    int t = threadIdx.x;
    if (t < 96) nrm[t] = fmaxf(sqrtf(sumsq[t]), 1e-12f);
    __syncthreads();
    float tmp = temp[0];
    if (t < 48) {
        float row[48];
        float mx = -1e30f;
#pragma unroll
        for (int d = 0; d < 48; d++) {
            float l = S[t*48+d] / (nrm[t]*nrm[48+d]) * tmp;
            row[d] = l; mx = fmaxf(mx, l);
        }
        float sum = 0.f;
#pragma unroll
        for (int d = 0; d < 48; d++) { float e = expf(row[d]-mx); sum += e; row[d] = e; }
        float inv = 1.f/sum;
#pragma unroll
        for (int d = 0; d < 48; d++) attn[t][d] = row[d]*inv;
    }
    __syncthreads();
    for (int idx = t; idx < 2304; idx += 256) {
        int cp = idx/48, d = idx%48;
        float acc = 0.f;
#pragma unroll
        for (int c = 0; c < 48; c++) acc += po_w[cp*48+c] * attn[c][d];
        M[idx] = acc;
    }
}

// ---------------- first = patch + M @ v (in place over bf16 patch, 2px/thread) ----------------
__global__ __launch_bounds__(256) void k_attnv(const bf16* __restrict__ v,
                                               const float* __restrict__ M,
                                               bf16* __restrict__ patch)
{
    __shared__ float Ms[48*48];
    for (int i = threadIdx.x; i < 2304; i += 256) Ms[i] = M[i];
    __syncthreads();
    int p = (blockIdx.x*256 + threadIdx.x)*2;
    float v0[48], v1[48];
#pragma unroll
    for (int i = 0; i < 48; i++) {
        unsigned int word = *(const unsigned int*)&v[(size_t)i*NPIX + p];
        fu c0, c1; c0.u = word << 16; c1.u = word & 0xffff0000u;
        v0[i] = c0.f; v1[i] = c1.f;
    }
    for (int oc = 0; oc < 48; oc++) {
        const float4* wr = (const float4*)&Ms[oc*48];
        float a0 = 0.f, a1 = 0.f;
#pragma unroll
        for (int i = 0; i < 12; i++) {
            float4 w4 = wr[i];
            a0 += w4.x*v0[4*i] + w4.y*v0[4*i+1] + w4.z*v0[4*i+2] + w4.w*v0[4*i+3];
            a1 += w4.x*v1[4*i] + w4.y*v1[4*i+1] + w4.z*v1[4*i+2] + w4.w*v1[4*i+3];
        }
        unsigned int* pp = (unsigned int*)&patch[(size_t)oc*NPIX + p];
        unsigned int old = *pp;
        fu f0, f1; f0.u = old << 16; f1.u = old & 0xffff0000u;
        bu b0, b1; b0.b = f2b(f0.f + a0); b1.b = f2b(f1.f + a1);
        *pp = (unsigned int)b0.u | ((unsigned int)b1.u << 16);
    }
}

// ---------------- depthwise 3x3 both halves + gelu(x1)*x2, rolling window: 8 rows/wave ----------------
__global__ __launch_bounds__(256) void k_dw_glu(const bf16* __restrict__ h1,
                                                const float* __restrict__ w,
                                                bf16* __restrict__ g)
{
    int ch = blockIdx.y;   // 0..126
    int lane = threadIdx.x & 63, wv = threadIdx.x >> 6;
    int row0 = blockIdx.x*32 + wv*8;
    int col = lane*8;
    float w1[9], w2[9];
#pragma unroll
    for (int i = 0; i < 9; i++) { w1[i] = w[ch*9+i]; w2[i] = w[(ch+127)*9+i]; }
    const bf16* i1 = h1 + (size_t)ch*NPIX;
    const bf16* i2 = h1 + (size_t)(ch+127)*NPIX;
    bf16* op = g + (size_t)ch*NPIX;
    float aa[3][8], bb[3][8];
    float lfa[3], rta[3], lfb[3], rtb[3];

    auto loadrow = [&](int s, int rr) {
        if (rr >= 0 && rr < HW) {
            ld_bf8(i1 + rr*HW + col, aa[s]);
            ld_bf8(i2 + rr*HW + col, bb[s]);
        } else {
#pragma unroll
            for (int j = 0; j < 8; j++) { aa[s][j] = 0.f; bb[s][j] = 0.f; }
        }
        float l1 = __shfl_up(aa[s][7],1);   lfa[s] = (lane==0)  ? 0.f : l1;
        float r1 = __shfl_down(aa[s][0],1); rta[s] = (lane==63) ? 0.f : r1;
        float l2 = __shfl_up(bb[s][7],1);   lfb[s] = (lane==0)  ? 0.f : l2;
        float r2 = __shfl_down(bb[s][0],1); rtb[s] = (lane==63) ? 0.f : r2;
    };
    loadrow(0, row0-1);
    loadrow(1, row0);
#pragma unroll
    for (int r = 0; r < 8; r++) {
        loadrow((r+2)%3, row0 + r + 1);
        const int s0 = r%3, s1 = (r+1)%3, s2 = (r+2)%3;
        float o[8];
#pragma unroll
        for (int j = 0; j < 8; j++) {
            float sum1 = 0.f, sum2 = 0.f;
#pragma unroll
            for (int kr = 0; kr < 3; kr++) {
                const int ss = (kr==0) ? s0 : (kr==1) ? s1 : s2;
                float xm = (j==0) ? lfa[ss] : aa[ss][j-1];
                float x0 = aa[ss][j];
                float xp = (j==7) ? rta[ss] : aa[ss][j+1];
                sum1 += w1[kr*3+0]*xm + w1[kr*3+1]*x0 + w1[kr*3+2]*xp;
                float ym = (j==0) ? lfb[ss] : bb[ss][j-1];
                float y0 = bb[ss][j];
                float yp = (j==7) ? rtb[ss] : bb[ss][j+1];
                sum2 += w2[kr*3+0]*ym + w2[kr*3+1]*y0 + w2[kr*3+2]*yp;
            }
            float ge = 0.5f*sum1*(1.f + erff(sum1*0.70710678118654752f));
            o[j] = ge*sum2;
        }
        st_bf8(op + (row0 + r)*HW + col, o);
    }
}

// ---------------- fo 1x1 conv (127 -> 48) via MFMA + residual, fp32 out ----------------
__global__ __launch_bounds__(256) void k_fo_mfma(const bf16* __restrict__ g,
                                                 const s16x8* __restrict__ wfo,   // [48][16 blocks]
                                                 const bf16* __restrict__ first,
                                                 float* __restrict__ out)
{
    __shared__ s16x8 glds[256*16];   // 64 KB, swizzled
    int t = threadIdx.x;
    int base = blockIdx.x*256;
    int px = base + t;
#pragma unroll
    for (int kb = 0; kb < 16; kb++) {
        union { s16x8 v; unsigned short us[8]; } pk;
#pragma unroll
        for (int j = 0; j < 8; j++) {
            int c = kb*8 + j;
            if (c < 127) { bu b; b.b = g[(size_t)c*NPIX + px]; pk.us[j] = b.u; }
            else pk.us[j] = 0;
        }
        glds[t*16 + (kb ^ (t & 15))] = pk.v;
    }
    __syncthreads();
    int lane = t & 63, wv = t >> 6;
    int q = lane >> 4, n = lane & 15;
    s16x8 a[3][4];
#pragma unroll
    for (int mt = 0; mt < 3; mt++) {
        int oc = mt*16 + n;
#pragma unroll
        for (int kc = 0; kc < 4; kc++)
            a[mt][kc] = wfo[oc*16 + kc*4 + q];
    }
#pragma unroll 1
    for (int ni = 0; ni < 4; ni++) {
        int nt = wv*4 + ni;
        int npx = nt*16 + n;
        s16x8 b[4];
#pragma unroll
        for (int kc = 0; kc < 4; kc++)
            b[kc] = glds[npx*16 + ((kc*4 + q) ^ (npx & 15))];
        size_t pxg = base + npx;
#pragma unroll
        for (int mt = 0; mt < 3; mt++) {
            f32x4 acc = {0.f, 0.f, 0.f, 0.f};
#pragma unroll
            for (int kc = 0; kc < 4; kc++)
                acc = __builtin_amdgcn_mfma_f32_16x16x32_bf16(a[mt][kc], b[kc], acc, 0, 0, 0);
            int ocb = mt*16 + q*4;
#pragma unroll
            for (int r = 0; r < 4; r++) {
                int oc = ocb + r;
                out[(size_t)oc*NPIX + pxg] = b2f(first[(size_t)oc*NPIX + pxg]) + acc[r];
            }
        }
    }
}

extern "C" void kernel_launch(void* const* d_in, const int* in_sizes, int n_in,
                              void* d_out, int out_size, void* d_ws, size_t ws_size,
                              hipStream_t stream)
{
    const float* x     = (const float*)d_in[0];
    const float* pe_w  = (const float*)d_in[1];
    const float* n1w   = (const float*)d_in[2];
    const float* n1b   = (const float*)d_in[3];
    const float* temp  = (const float*)d_in[4];
    const float* qkvw  = (const float*)d_in[5];
    const float* qkvdw = (const float*)d_in[6];
    const float* pow_  = (const float*)d_in[7];
    const float* n2w   = (const float*)d_in[8];
    const float* n2b   = (const float*)d_in[9];
    const float* piw   = (const float*)d_in[10];
    const float* ffndw = (const float*)d_in[11];
    const float* fow   = (const float*)d_in[12];
    float* out = (float*)d_out;

    bf16*  Pb = (bf16*)d_ws;
    bf16*  A  = Pb + (size_t)48*NPIX;          // region reused: H1 (254 planes)
    bf16*  Bq = A + (size_t)144*NPIX;          // qkv post-dw (q,k,v)
    bf16*  H1 = A;
    bf16*  G  = A + (size_t)254*NPIX;
    bf16*  WQ = A + (size_t)381*NPIX;          // 144*64
    bf16*  WP = WQ + 144*64;                   // 256*64
    bf16*  WF = WP + 256*64;                   // 48*128
    float* SM0 = (float*)(A + (size_t)384*NPIX);   // per-batch: sumsq[96], S[2304], M[2304]
    float* SM1 = SM0 + 4704;

    dim3 blk(256);
    int nb1 = NPIX/256;   // 1px/thread MFMA kernels
    int nb2 = NPIX/512;   // 2px/thread (attnv)
    int nr  = HW/4;       // k_pe: 4 rows/block
    int nrw = HW/32;      // rolling dw kernels: 32 rows/block

    k_prep<<<dim3(143), blk, 0, stream>>>(qkvw, piw, fow, WQ, WP, WF, SM0, SM1);

    for (int b = 0; b < 2; b++) {
        const float* xb   = x   + (size_t)b*3*NPIX;
        float*       outb = out + (size_t)b*48*NPIX;
        float* SMb   = b ? SM1 : SM0;
        float* sumsq = SMb;
        float* S     = SMb + 96;
        float* M     = SMb + 2400;

        k_pe<<<dim3(nr), blk, 0, stream>>>(xb, pe_w, Pb);
        k_ln_dw<<<dim3(HW/32, HW/8), blk, 0, stream>>>(Pb, n1w, n1b, (const s16x8*)WQ, qkvdw, Bq);
        k_qkt<<<dim3(NPIX/1024), dim3(512), 0, stream>>>(Bq, Bq + (size_t)48*NPIX, S, sumsq);
        k_attn_final<<<dim3(1), blk, 0, stream>>>(S, sumsq, pow_, temp, M);
        k_attnv<<<dim3(nb2), blk, 0, stream>>>(Bq + (size_t)96*NPIX, M, Pb);
        k_ln_mm_mfma<256,254,4><<<dim3(nb1), blk, 0, stream>>>(Pb, n2w, n2b, (const s16x8*)WP, H1);
        k_dw_glu<<<dim3(nrw, 127), blk, 0, stream>>>(H1, ffndw, G);
        k_fo_mfma<<<dim3(nb1), blk, 0, stream>>>(G, (const s16x8*)WF, Pb, outb);
    }
}